// Round 6
// baseline (80.603 us; speedup 1.0000x reference)
//
#include <hip/hip_runtime.h>
#include <hip/hip_bf16.h>

#define T_SEQ 2048
#define EMB   128
#define H     16
#define BATCH 8
#define VSTR  2064        // Vt row stride (elems), non-power-of-2 (r11)
// Q pre-scale: 1/sqrt(16) * log2(e)  -> scores in log2 domain
#define QSCALE 0.360673760222241f

// exp2 via clang builtin (r8-proven); __exp2f clashes with glibc macro.
#define EXP2F(x) __builtin_amdgcn_exp2f(x)

typedef short short8_t __attribute__((ext_vector_type(8)));  // 8 bf16
typedef float f32x4    __attribute__((ext_vector_type(4)));  // MFMA C/D frag

__device__ __forceinline__ unsigned short f2bf(float f) {
    __hip_bfloat16 h = __float2bfloat16(f);   // RNE
    return *reinterpret_cast<unsigned short*>(&h);
}

// ---------------------------------------------------------------------------
// Kernel 1 (r18): K/V projection only (Q moved into the attn kernel).
// Grid 1024 x 128 threads: block owns 16 rows; wave 0 -> K, wave 1 -> V.
// No LDS, no barriers. W fragments loaded straight from global (L1/L2-hot).
// 2/3 the work of the r15 qkv kernel on the same block parallelism.
// ---------------------------------------------------------------------------
__global__ __launch_bounds__(128) void kv_kernel(
    const float* __restrict__ x,
    const float* __restrict__ Wk,
    const float* __restrict__ Wv,
    unsigned short* __restrict__ Kbf,
    unsigned short* __restrict__ Vt)
{
    const int tid  = threadIdx.x;
    const int wv   = tid >> 6;        // 0:K 1:V
    const int lane = tid & 63;
    const int q    = lane >> 4;
    const int n    = lane & 15;
    const int r0   = blockIdx.x * 16;

    const float* Wm = (wv == 0) ? Wk : Wv;
    const float* xr = x + (size_t)(r0 + n) * EMB;

    f32x4 a = {0.f, 0.f, 0.f, 0.f};
#pragma unroll
    for (int t = 0; t < 4; ++t) {
        const int k0 = t * 32 + q * 8;
        float4 xa = *reinterpret_cast<const float4*>(xr + k0);
        float4 xb = *reinterpret_cast<const float4*>(xr + k0 + 4);
        union { unsigned short s[8]; short8_t v; } xf;
        xf.s[0]=f2bf(xa.x); xf.s[1]=f2bf(xa.y); xf.s[2]=f2bf(xa.z); xf.s[3]=f2bf(xa.w);
        xf.s[4]=f2bf(xb.x); xf.s[5]=f2bf(xb.y); xf.s[6]=f2bf(xb.z); xf.s[7]=f2bf(xb.w);
        // B fragment: lane(q,n) needs W[k0+j][n], j=0..7 (row stride H=16).
        union { unsigned short s[8]; short8_t v; } wf;
#pragma unroll
        for (int j = 0; j < 8; ++j)
            wf.s[j] = f2bf(Wm[(size_t)(k0 + j) * H + n]);
        a = __builtin_amdgcn_mfma_f32_16x16x32_bf16(xf.v, wf.v, a, 0, 0, 0);
    }

    // C/D frag: lane(q,n) holds rows r0+4q+r, col n.
    const int grow = r0 + q * 4;
    if (wv == 0) {
#pragma unroll
        for (int r = 0; r < 4; ++r)
            Kbf[(size_t)(grow + r) * H + n] = f2bf(a[r]);
    } else {
        const int b   = grow >> 11;
        const int ib0 = grow & 2047;
        union { unsigned short s[4]; unsigned long long u; } vp;
        vp.s[0]=f2bf(a[0]); vp.s[1]=f2bf(a[1]); vp.s[2]=f2bf(a[2]); vp.s[3]=f2bf(a[3]);
        *reinterpret_cast<unsigned long long*>(
            Vt + ((size_t)b * H + n) * VSTR + ib0) = vp.u;
    }
}

// ---------------------------------------------------------------------------
// Kernel 2 (r18): split-K flash attention with INLINE Q projection.
// Each block computes Q for its own 16 rows (16x128 @ 128x16, one 4-step
// MFMA chain per wave, ~32K MACs — duplicated across the 4 waves, trivial).
// The projection C-fragment (rows 4q+r, col n) is transposed to the
// S-MFMA B-fragment layout (row n, dims 8q..) via a 2 KB per-wave LDS
// bounce — same wave-internal LDS exchange pattern as Pbuf (no barrier).
// Rest is the r16 body: 4-way wave split-K, K-tile prefetch, no-max
// log2-domain softmax, plain-sum combine; heavy tiles dispatched first.
// ---------------------------------------------------------------------------
__global__ __launch_bounds__(256, 4) void attn_fused(
    const float* __restrict__ x,
    const float* __restrict__ Wq,
    const unsigned short* __restrict__ Kbf,
    const unsigned short* __restrict__ Vt,
    float* __restrict__ out)
{
    __shared__ unsigned int Pbuf[4][16][68];   // 17.4 KB (wave-private P^T)
    __shared__ float CombA[4][16][20];         // 5 KB  (padded: bank-spread)
    __shared__ float CombL[4][16];
    __shared__ unsigned short Qtmp[4][16][16]; // 2 KB  (wave-private Q tile)

    const int qt = (T_SEQ / 16 - 1) - blockIdx.x;  // heavy tiles first
    const int b  = blockIdx.y;
    const int i0 = qt << 4;
    const int nc = (qt >> 3) + 1;              // chunks of 128 K cols

    const int tid  = threadIdx.x;
    const int wv   = tid >> 6;
    const int lane = tid & 63;
    const int q    = lane >> 4;
    const int n    = lane & 15;
    const int irow = i0 + n;

    const unsigned short* Kp = Kbf + (size_t)b * T_SEQ * H;
    const unsigned short* vrow = Vt + (size_t)b * H * VSTR + (size_t)n * VSTR;

    // --- K prefetch prologue first (independent loads, fire ASAP). ---------
    int c = wv;
    short8_t kcur[8];
#pragma unroll
    for (int s = 0; s < 8; ++s) kcur[s] = (short8_t){0,0,0,0,0,0,0,0};
    if (c < nc && q < 2) {
        const int j0 = c << 7;
#pragma unroll
        for (int s = 0; s < 8; ++s)
            kcur[s] = *reinterpret_cast<const short8_t*>(
                          Kp + (size_t)(j0 + s * 16 + n) * H + q * 8);
    }

    // --- Inline Q projection for this block's 16 rows (hides under K). -----
    {
        const float* xr = x + ((size_t)b * T_SEQ + i0 + n) * EMB;
        f32x4 aq = {0.f, 0.f, 0.f, 0.f};
#pragma unroll
        for (int t = 0; t < 4; ++t) {
            const int k0 = t * 32 + q * 8;
            float4 xa = *reinterpret_cast<const float4*>(xr + k0);
            float4 xb = *reinterpret_cast<const float4*>(xr + k0 + 4);
            union { unsigned short s[8]; short8_t v; } xf;
            xf.s[0]=f2bf(xa.x); xf.s[1]=f2bf(xa.y); xf.s[2]=f2bf(xa.z); xf.s[3]=f2bf(xa.w);
            xf.s[4]=f2bf(xb.x); xf.s[5]=f2bf(xb.y); xf.s[6]=f2bf(xb.z); xf.s[7]=f2bf(xb.w);
            union { unsigned short s[8]; short8_t v; } wf;
#pragma unroll
            for (int j = 0; j < 8; ++j)
                wf.s[j] = f2bf(Wq[(size_t)(k0 + j) * H + n]);
            aq = __builtin_amdgcn_mfma_f32_16x16x32_bf16(xf.v, wf.v, aq, 0, 0, 0);
        }
        // C-frag (row 4q+r, dim n) -> LDS -> B-frag (row n, dims 8q..8q+7).
#pragma unroll
        for (int r = 0; r < 4; ++r)
            Qtmp[wv][4 * q + r][n] = f2bf(aq[r] * QSCALE);
    }
    short8_t qf = {0,0,0,0,0,0,0,0};
    if (q < 2)
        qf = *reinterpret_cast<const short8_t*>(&Qtmp[wv][n][8 * q]);

    f32x4 acc = {0.f, 0.f, 0.f, 0.f};          // O^T fragment (fp32, carried)
    float l = 0.f;                             // per-lane partial denom

    for (; c < nc; c += 4) {
        const int j0 = c << 7;

        // S MFMAs consume the prefetched K fragments.
        f32x4 S[8];
#pragma unroll
        for (int s = 0; s < 8; ++s) {
            f32x4 z = {0.f, 0.f, 0.f, 0.f};
            S[s] = __builtin_amdgcn_mfma_f32_16x16x32_bf16(kcur[s], qf, z, 0, 0, 0);
        }
        // Prefetch next chunk's K (latency hides under softmax+PV below).
        const int c2 = c + 4;
        if (c2 < nc && q < 2) {
            const int j2 = c2 << 7;
#pragma unroll
            for (int s = 0; s < 8; ++s)
                kcur[s] = *reinterpret_cast<const short8_t*>(
                              Kp + (size_t)(j2 + s * 16 + n) * H + q * 8);
        }
        // V fragments issued early (consumed after softmax).
        short8_t vf[4];
#pragma unroll
        for (int h = 0; h < 4; ++h)
            vf[h] = *reinterpret_cast<const short8_t*>(vrow + j0 + h * 32 + q * 8);

        // Causal mask: exactly the diagonal chunk satisfies j0+127 > i0.
        // Masked entries -> -1e30 -> exp2 flushes to exactly 0.
        if (j0 + 127 > i0) {
#pragma unroll
            for (int s = 0; s < 8; ++s) {
                const int kb = j0 + s * 16 + q * 4;
#pragma unroll
                for (int rr = 0; rr < 4; ++rr)
                    S[s][rr] = (kb + rr <= irow) ? S[s][rr] : -1e30f;
            }
        }

        // exp2 (no max shift needed in log2 domain), per-lane partial sum,
        // pack P^T into LDS (wave-private).
        float lc = 0.f;
#pragma unroll
        for (int s = 0; s < 8; ++s) {
            float e0 = EXP2F(S[s][0]);
            float e1 = EXP2F(S[s][1]);
            float e2 = EXP2F(S[s][2]);
            float e3 = EXP2F(S[s][3]);
            lc += (e0 + e1) + (e2 + e3);
            unsigned int b0 = __builtin_bit_cast(unsigned int, e0);
            unsigned int b1 = __builtin_bit_cast(unsigned int, e1);
            unsigned int b2 = __builtin_bit_cast(unsigned int, e2);
            unsigned int b3 = __builtin_bit_cast(unsigned int, e3);
            unsigned long long pw =
                (unsigned long long)((b1 & 0xffff0000u) | (b0 >> 16)) |
                ((unsigned long long)((b3 & 0xffff0000u) | (b2 >> 16)) << 32);
            *reinterpret_cast<unsigned long long*>(&Pbuf[wv][n][8 * s + 2 * q]) = pw;
        }
        l += lc;

        // PV: O^T += V^T · P^T (4 MFMAs, b128 Pbuf reads, C carries acc).
#pragma unroll
        for (int h = 0; h < 4; ++h) {
            uint4 p4 = *reinterpret_cast<const uint4*>(&Pbuf[wv][n][16 * h + 4 * q]);
            union { uint4 u; short8_t v; } pu; pu.u = p4;
            acc = __builtin_amdgcn_mfma_f32_16x16x32_bf16(vf[h], pu.v, acc, 0, 0, 0);
        }
    }

    // Per-wave row denominator: sum partials across the 4 q lanes.
    l += __shfl_xor(l, 16);
    l += __shfl_xor(l, 32);

    // Publish wave partial: lane (q,n) holds O_w[row=i0+n][dim=4q+r].
    *reinterpret_cast<float4*>(&CombA[wv][n][4 * q]) =
        (float4){acc[0], acc[1], acc[2], acc[3]};
    if (q == 0) CombL[wv][n] = l;
    __syncthreads();

    // Combine 4 wave partials: plain sums (no LSE needed — shared shift 0).
    // Empty waves contribute acc=0, l=0.
    {
        const int row = tid >> 4;
        const int d   = tid & 15;
        float L = 0.f, O = 0.f;
#pragma unroll
        for (int w = 0; w < 4; ++w) {
            L += CombL[w][row];
            O += CombA[w][row][d];
        }
        out[((size_t)b * T_SEQ + i0 + row) * H + d] = O / L;
    }
}

// ---------------------------------------------------------------------------
extern "C" void kernel_launch(void* const* d_in, const int* in_sizes, int n_in,
                              void* d_out, int out_size, void* d_ws, size_t ws_size,
                              hipStream_t stream)
{
    const float* x  = (const float*)d_in[0];
    const float* Wq = (const float*)d_in[1];
    const float* Wk = (const float*)d_in[2];
    const float* Wv = (const float*)d_in[3];
    float* out = (float*)d_out;

    const size_t NE = (size_t)BATCH * T_SEQ * H;      // 262144 elems per buf
    unsigned short* Kbf = (unsigned short*)d_ws;
    unsigned short* Vt  = Kbf + NE;                   // BATCH*H*VSTR elems

    kv_kernel<<<BATCH * T_SEQ / 16, 128, 0, stream>>>(x, Wk, Wv, Kbf, Vt);
    attn_fused<<<dim3(T_SEQ / 16, BATCH), 256, 0, stream>>>(
        x, Wq, Kbf, Vt, out);
}

// Round 7
// 76.113 us; speedup vs baseline: 1.0590x; 1.0590x over previous
//
#include <hip/hip_runtime.h>
#include <hip/hip_bf16.h>

#define T_SEQ 2048
#define EMB   128
#define H     16
#define BATCH 8
#define VSTR  2064        // Vt row stride (elems), non-power-of-2 (r11)
// Q pre-scale: 1/sqrt(16) * log2(e)  -> scores in log2 domain
#define QSCALE 0.360673760222241f

// exp2 via clang builtin (r8-proven); __exp2f clashes with glibc macro.
#define EXP2F(x) __builtin_amdgcn_exp2f(x)

typedef short short8_t __attribute__((ext_vector_type(8)));  // 8 bf16
typedef float f32x4    __attribute__((ext_vector_type(4)));  // MFMA C/D frag

__device__ __forceinline__ unsigned short f2bf(float f) {
    __hip_bfloat16 h = __float2bfloat16(f);   // RNE
    return *reinterpret_cast<unsigned short*>(&h);
}

// ---------------------------------------------------------------------------
// Kernel 1 (r15, proven): QKV projection, latency-optimized re-grid.
// Grid 1024 x 192 threads: block owns 16 rows; wave w computes matrix w
// (Q/K/V). No LDS, no barriers. W fragments loaded straight from global
// (8 KB per matrix -> L1/L2-resident after first touch).
// ---------------------------------------------------------------------------
__global__ __launch_bounds__(192) void qkv_kernel(
    const float* __restrict__ x,
    const float* __restrict__ Wq,
    const float* __restrict__ Wk,
    const float* __restrict__ Wv,
    unsigned short* __restrict__ Qbf,
    unsigned short* __restrict__ Kbf,
    unsigned short* __restrict__ Vt)
{
    const int tid  = threadIdx.x;
    const int wv   = tid >> 6;        // 0:Q 1:K 2:V
    const int lane = tid & 63;
    const int q    = lane >> 4;
    const int n    = lane & 15;
    const int r0   = blockIdx.x * 16;

    const float* Wm = (wv == 0) ? Wq : (wv == 1) ? Wk : Wv;
    const float* xr = x + (size_t)(r0 + n) * EMB;

    f32x4 a = {0.f, 0.f, 0.f, 0.f};
#pragma unroll
    for (int t = 0; t < 4; ++t) {
        const int k0 = t * 32 + q * 8;
        float4 xa = *reinterpret_cast<const float4*>(xr + k0);
        float4 xb = *reinterpret_cast<const float4*>(xr + k0 + 4);
        union { unsigned short s[8]; short8_t v; } xf;
        xf.s[0]=f2bf(xa.x); xf.s[1]=f2bf(xa.y); xf.s[2]=f2bf(xa.z); xf.s[3]=f2bf(xa.w);
        xf.s[4]=f2bf(xb.x); xf.s[5]=f2bf(xb.y); xf.s[6]=f2bf(xb.z); xf.s[7]=f2bf(xb.w);
        // B fragment: lane(q,n) needs W[k0+j][n], j=0..7 (row stride H=16).
        union { unsigned short s[8]; short8_t v; } wf;
#pragma unroll
        for (int j = 0; j < 8; ++j)
            wf.s[j] = f2bf(Wm[(size_t)(k0 + j) * H + n]);
        a = __builtin_amdgcn_mfma_f32_16x16x32_bf16(xf.v, wf.v, a, 0, 0, 0);
    }

    // C/D frag: lane(q,n) holds rows r0+4q+r, col n.
    const int grow = r0 + q * 4;
    if (wv == 0) {
#pragma unroll
        for (int r = 0; r < 4; ++r)
            Qbf[(size_t)(grow + r) * H + n] = f2bf(a[r] * QSCALE);
    } else if (wv == 1) {
#pragma unroll
        for (int r = 0; r < 4; ++r)
            Kbf[(size_t)(grow + r) * H + n] = f2bf(a[r]);
    } else {
        const int b   = grow >> 11;
        const int ib0 = grow & 2047;
        union { unsigned short s[4]; unsigned long long u; } vp;
        vp.s[0]=f2bf(a[0]); vp.s[1]=f2bf(a[1]); vp.s[2]=f2bf(a[2]); vp.s[3]=f2bf(a[3]);
        *reinterpret_cast<unsigned long long*>(
            Vt + ((size_t)b * H + n) * VSTR + ib0) = vp.u;
    }
}

// ---------------------------------------------------------------------------
// Kernel 2 (r19): split-K flash attention, 8-WAY wave split per block.
// 512 threads (8 waves); grid (128,8) = 1024 blocks = 4 blocks/CU =
// 2048 threads/CU (full capacity, 32 waves/CU). Wave w handles chunks
// c = w, w+8, ... -> heavy tiles (nc=16) run at most 2 serial chunk
// iterations (was 4 with the r16 4-way split), halving the per-block
// critical chain. Pbuf is unioned with the combine buffers (disjoint
// lifetimes, barrier-separated) to keep LDS at 34.8 KB -> 4 blocks/CU.
// Per-chunk body unchanged (K prefetch, no-max log2 softmax); combine
// is a plain sum over 8 wave partials. Heavy tiles dispatched first.
// ---------------------------------------------------------------------------
__global__ __launch_bounds__(512, 4) void attn_fused(
    const unsigned short* __restrict__ Qbf,
    const unsigned short* __restrict__ Kbf,
    const unsigned short* __restrict__ Vt,
    float* __restrict__ out)
{
    __shared__ union {
        unsigned int P[8][16][68];             // 34.8 KB wave-private P^T
        struct {
            float A[8][16][20];                // padded: 16B-aligned rows
            float L[8][16];
        } comb;
    } sh;

    const int qt = (T_SEQ / 16 - 1) - blockIdx.x;  // heavy tiles first
    const int b  = blockIdx.y;
    const int i0 = qt << 4;
    const int nc = (qt >> 3) + 1;              // chunks of 128 K cols

    const int tid  = threadIdx.x;
    const int wv   = tid >> 6;                 // 0..7
    const int lane = tid & 63;
    const int q    = lane >> 4;
    const int n    = lane & 15;
    const int irow = i0 + n;

    const unsigned short* Qp = Qbf + (size_t)b * T_SEQ * H;
    const unsigned short* Kp = Kbf + (size_t)b * T_SEQ * H;
    const unsigned short* vrow = Vt + (size_t)b * H * VSTR + (size_t)n * VSTR;

    // Q loaded once (all 8 waves read the same 16 rows; L1-resident).
    short8_t qf = {0,0,0,0,0,0,0,0};
    if (q < 2)
        qf = *reinterpret_cast<const short8_t*>(Qp + (size_t)irow * H + q * 8);

    f32x4 acc = {0.f, 0.f, 0.f, 0.f};          // O^T fragment (fp32, carried)
    float l = 0.f;                             // per-lane partial denom

    // K prefetch prologue: first chunk's 8 fragments into registers.
    int c = wv;
    short8_t kcur[8];
#pragma unroll
    for (int s = 0; s < 8; ++s) kcur[s] = (short8_t){0,0,0,0,0,0,0,0};
    if (c < nc && q < 2) {
        const int j0 = c << 7;
#pragma unroll
        for (int s = 0; s < 8; ++s)
            kcur[s] = *reinterpret_cast<const short8_t*>(
                          Kp + (size_t)(j0 + s * 16 + n) * H + q * 8);
    }

    for (; c < nc; c += 8) {
        const int j0 = c << 7;

        // S MFMAs consume the prefetched K fragments.
        f32x4 S[8];
#pragma unroll
        for (int s = 0; s < 8; ++s) {
            f32x4 z = {0.f, 0.f, 0.f, 0.f};
            S[s] = __builtin_amdgcn_mfma_f32_16x16x32_bf16(kcur[s], qf, z, 0, 0, 0);
        }
        // Prefetch next chunk's K (latency hides under softmax+PV below).
        const int c2 = c + 8;
        if (c2 < nc && q < 2) {
            const int j2 = c2 << 7;
#pragma unroll
            for (int s = 0; s < 8; ++s)
                kcur[s] = *reinterpret_cast<const short8_t*>(
                              Kp + (size_t)(j2 + s * 16 + n) * H + q * 8);
        }
        // V fragments issued early (consumed after softmax).
        short8_t vf[4];
#pragma unroll
        for (int h = 0; h < 4; ++h)
            vf[h] = *reinterpret_cast<const short8_t*>(vrow + j0 + h * 32 + q * 8);

        // Causal mask: exactly the diagonal chunk satisfies j0+127 > i0.
        // Masked entries -> -1e30 -> exp2 flushes to exactly 0.
        if (j0 + 127 > i0) {
#pragma unroll
            for (int s = 0; s < 8; ++s) {
                const int kb = j0 + s * 16 + q * 4;
#pragma unroll
                for (int rr = 0; rr < 4; ++rr)
                    S[s][rr] = (kb + rr <= irow) ? S[s][rr] : -1e30f;
            }
        }

        // exp2 (no max shift needed in log2 domain), per-lane partial sum,
        // pack P^T into LDS (wave-private slice of sh.P).
        float lc = 0.f;
#pragma unroll
        for (int s = 0; s < 8; ++s) {
            float e0 = EXP2F(S[s][0]);
            float e1 = EXP2F(S[s][1]);
            float e2 = EXP2F(S[s][2]);
            float e3 = EXP2F(S[s][3]);
            lc += (e0 + e1) + (e2 + e3);
            unsigned int b0 = __builtin_bit_cast(unsigned int, e0);
            unsigned int b1 = __builtin_bit_cast(unsigned int, e1);
            unsigned int b2 = __builtin_bit_cast(unsigned int, e2);
            unsigned int b3 = __builtin_bit_cast(unsigned int, e3);
            unsigned long long pw =
                (unsigned long long)((b1 & 0xffff0000u) | (b0 >> 16)) |
                ((unsigned long long)((b3 & 0xffff0000u) | (b2 >> 16)) << 32);
            *reinterpret_cast<unsigned long long*>(&sh.P[wv][n][8 * s + 2 * q]) = pw;
        }
        l += lc;

        // PV: O^T += V^T · P^T (4 MFMAs, b128 P reads, C carries acc).
#pragma unroll
        for (int h = 0; h < 4; ++h) {
            uint4 p4 = *reinterpret_cast<const uint4*>(&sh.P[wv][n][16 * h + 4 * q]);
            union { uint4 u; short8_t v; } pu; pu.u = p4;
            acc = __builtin_amdgcn_mfma_f32_16x16x32_bf16(vf[h], pu.v, acc, 0, 0, 0);
        }
    }

    // Per-wave row denominator: sum partials across the 4 q lanes.
    l += __shfl_xor(l, 16);
    l += __shfl_xor(l, 32);

    // All waves must be done with sh.P before comb (aliased) is written.
    __syncthreads();

    // Publish wave partial: lane (q,n) holds O_w[row=i0+n][dim=4q+r].
    // Empty waves (loop never ran) publish acc=0, l=0 (plain-sum neutral).
    *reinterpret_cast<float4*>(&sh.comb.A[wv][n][4 * q]) =
        (float4){acc[0], acc[1], acc[2], acc[3]};
    if (q == 0) sh.comb.L[wv][n] = l;
    __syncthreads();

    // Combine 8 wave partials: plain sums (shared shift 0 -> no LSE).
    if (tid < 256) {
        const int row = tid >> 4;
        const int d   = tid & 15;
        float L = 0.f, O = 0.f;
#pragma unroll
        for (int w = 0; w < 8; ++w) {
            L += sh.comb.L[w][row];
            O += sh.comb.A[w][row][d];
        }
        out[((size_t)b * T_SEQ + i0 + row) * H + d] = O / L;
    }
}

// ---------------------------------------------------------------------------
extern "C" void kernel_launch(void* const* d_in, const int* in_sizes, int n_in,
                              void* d_out, int out_size, void* d_ws, size_t ws_size,
                              hipStream_t stream)
{
    const float* x  = (const float*)d_in[0];
    const float* Wq = (const float*)d_in[1];
    const float* Wk = (const float*)d_in[2];
    const float* Wv = (const float*)d_in[3];
    float* out = (float*)d_out;

    const size_t NE = (size_t)BATCH * T_SEQ * H;      // 262144 elems per buf
    unsigned short* Qbf = (unsigned short*)d_ws;
    unsigned short* Kbf = Qbf + NE;
    unsigned short* Vt  = Kbf + NE;                   // BATCH*H*VSTR elems

    qkv_kernel<<<BATCH * T_SEQ / 16, 192, 0, stream>>>(
        x, Wq, Wk, Wv, Qbf, Kbf, Vt);
    attn_fused<<<dim3(T_SEQ / 16, BATCH), 512, 0, stream>>>(Qbf, Kbf, Vt, out);
}